// Round 8
// baseline (36.034 us; speedup 1.0000x reference)
//
#include <hip/hip_runtime.h>

#define HD 1152          // hidden size
#define SQ 4096          // seq len
#define NB 256           // output bins (L)
#define BT 8             // batch
#define KK 4             // pool kernel size

typedef float f4 __attribute__((ext_vector_type(4)));   // native vec for nt builtins

// One block per (b, bin); 256 threads, each owns 16 consecutive tokens.
// Round-3 proven structure + nontemporal hs loads / out stores (hs is
// streamed exactly once -> don't pollute L1/L2).
__global__ void __launch_bounds__(256) k_pool(const int* __restrict__ pos,
                                              const float* __restrict__ hs,
                                              float* __restrict__ out,
                                              float* __restrict__ mask) {
    int bl = blockIdx.x;          // b*NB + l
    int b = bl >> 8;
    unsigned l = (unsigned)(bl & (NB - 1));
    int tid = threadIdx.x;
    int wv = tid >> 6, lane = tid & 63;

    __shared__ unsigned short list[SQ];
    __shared__ int wcnt[4];
    __shared__ int smax[4];

    // each thread owns tokens [16*tid, 16*tid+16): 32 ints = 8 int4
    const int tokbase = tid * 16;
    const int4* pp = (const int4*)(pos + (size_t)b * SQ * 2) + tid * 8;
    int4 q[8];
    #pragma unroll
    for (int j = 0; j < 8; ++j) q[j] = pp[j];   // {x0,y0,x1,y1} tokens 2j,2j+1

    // ---- phase 1: block max of x (clamped >= 0)
    int mx = -1;
    #pragma unroll
    for (int j = 0; j < 8; ++j) mx = max(mx, max(q[j].x, q[j].z));
    if (mx < 0) mx = 0;
    #pragma unroll
    for (int off = 32; off > 0; off >>= 1)
        mx = max(mx, __shfl_down(mx, off, 64));
    if (lane == 0) smax[wv] = mx;
    __syncthreads();
    const int mxq = (max(max(smax[0], smax[1]), max(smax[2], smax[3])) + 1) / KK;

    // ---- phase 2: flat ids + match mask + compaction
    unsigned m16 = 0;
    #pragma unroll
    for (int j = 0; j < 8; ++j) {
        int x0 = q[j].x, y0 = q[j].y, x1 = q[j].z, y1 = q[j].w;
        unsigned f0 = (unsigned)((max(x0, 0) >> 2) + mxq * (max(y0, 0) >> 2));
        unsigned f1 = (unsigned)((max(x1, 0) >> 2) + mxq * (max(y1, 0) >> 2));
        bool p0 = (x0 == -1) && (y0 == -1);
        bool p1 = (x1 == -1) && (y1 == -1);
        if (!p0 && f0 == l) m16 |= 1u << (2 * j);
        if (!p1 && f1 == l) m16 |= 1u << (2 * j + 1);
    }
    int cnt = __popc(m16);

    int pre = cnt;                      // inclusive wave prefix
    #pragma unroll
    for (int off = 1; off < 64; off <<= 1) {
        int n = __shfl_up(pre, off, 64);
        if (lane >= off) pre += n;
    }
    if (lane == 63) wcnt[wv] = pre;
    int excl = pre - cnt;
    __syncthreads();

    int woff = 0;
    #pragma unroll
    for (int v = 0; v < 4; ++v) if (v < wv) woff += wcnt[v];
    int total = wcnt[0] + wcnt[1] + wcnt[2] + wcnt[3];

    int r = woff + excl;
    unsigned m = m16;
    while (m) {
        int j = __ffs(m) - 1;
        m &= m - 1;
        list[r++] = (unsigned short)(tokbase + j);
    }
    __syncthreads();

    // ---- phase 3: gather-sum (288 f4/row; thread t owns col t, +256+t if t<32)
    f4 a0 = (f4)(0.f);
    f4 a1 = (f4)(0.f);
    const float* hb = hs + (size_t)b * SQ * HD;
    int i = 0;
    for (; i + 3 < total; i += 4) {
        const f4* r0 = (const f4*)(hb + (size_t)list[i]     * HD);
        const f4* r1 = (const f4*)(hb + (size_t)list[i + 1] * HD);
        const f4* r2 = (const f4*)(hb + (size_t)list[i + 2] * HD);
        const f4* r3 = (const f4*)(hb + (size_t)list[i + 3] * HD);
        f4 v0 = __builtin_nontemporal_load(&r0[tid]);
        f4 v1 = __builtin_nontemporal_load(&r1[tid]);
        f4 v2 = __builtin_nontemporal_load(&r2[tid]);
        f4 v3 = __builtin_nontemporal_load(&r3[tid]);
        a0 += v0 + v1 + v2 + v3;
        if (tid < HD / 4 - 256) {
            f4 u0 = __builtin_nontemporal_load(&r0[256 + tid]);
            f4 u1 = __builtin_nontemporal_load(&r1[256 + tid]);
            f4 u2 = __builtin_nontemporal_load(&r2[256 + tid]);
            f4 u3 = __builtin_nontemporal_load(&r3[256 + tid]);
            a1 += u0 + u1 + u2 + u3;
        }
    }
    for (; i < total; ++i) {
        const f4* r0 = (const f4*)(hb + (size_t)list[i] * HD);
        f4 v0 = __builtin_nontemporal_load(&r0[tid]);
        a0 += v0;
        if (tid < HD / 4 - 256) {
            f4 u0 = __builtin_nontemporal_load(&r0[256 + tid]);
            a1 += u0;
        }
    }

    const float scale = 2.1213203435596424f;   // sqrt(1152) / 16
    f4* o = (f4*)(out + (size_t)bl * HD);
    a0 *= scale;
    __builtin_nontemporal_store(a0, &o[tid]);
    if (tid < HD / 4 - 256) {
        a1 *= scale;
        __builtin_nontemporal_store(a1, &o[256 + tid]);
    }
    if (tid == 0) mask[bl] = (total > 0) ? 1.0f : 0.0f;
}

extern "C" void kernel_launch(void* const* d_in, const int* in_sizes, int n_in,
                              void* d_out, int out_size, void* d_ws, size_t ws_size,
                              hipStream_t stream) {
    const float* hs = (const float*)d_in[0];
    const int* pos = (const int*)d_in[1];
    float* out = (float*)d_out;                        // pooled [8,256,1152]
    float* mask = out + (size_t)BT * NB * HD;          // mask   [8,256]

    k_pool<<<BT * NB, 256, 0, stream>>>(pos, hs, out, mask);
}

// Round 9
// 32.700 us; speedup vs baseline: 1.1019x; 1.1019x over previous
//
#include <hip/hip_runtime.h>

#define HD 1152          // hidden size
#define SQ 4096          // seq len
#define NB 256           // output bins (L)
#define BT 8             // batch
#define KK 4             // pool kernel size

// One block per (b, bin). Each of the 256 threads owns 16 consecutive tokens
// (block covers the batch's full 4096 tokens exactly), so:
//   phase 1: per-batch max_x reduce comes free from registers
//   phase 2: flat bin ids in registers, 16-bit match mask, wave prefix-sum
//            compaction into an LDS token list (deterministic order)
//   phase 3: gather-sum the matching rows with float4 loads, 4-deep unroll
// NOTE: no min-waves launch bound (reg caps spilled this kernel twice) and no
// nontemporal hints (bypassing L2 cost 12%).
__global__ void __launch_bounds__(256) k_pool(const int* __restrict__ pos,
                                              const float* __restrict__ hs,
                                              float* __restrict__ out,
                                              float* __restrict__ mask) {
    int bl = blockIdx.x;          // b*NB + l
    int b = bl >> 8;
    unsigned l = (unsigned)(bl & (NB - 1));
    int tid = threadIdx.x;
    int wv = tid >> 6, lane = tid & 63;

    __shared__ unsigned short list[SQ];
    __shared__ int wcnt[4];
    __shared__ int smax[4];

    // each thread owns tokens [16*tid, 16*tid+16): 32 ints = 8 int4
    const int tokbase = tid * 16;
    const int4* pp = (const int4*)(pos + (size_t)b * SQ * 2) + tid * 8;
    int4 q[8];
    #pragma unroll
    for (int j = 0; j < 8; ++j) q[j] = pp[j];   // {x0,y0,x1,y1} tokens 2j,2j+1

    // ---- phase 1: block max of x (clamped >= 0)
    int mx = 0;
    #pragma unroll
    for (int j = 0; j < 8; ++j) mx = max(mx, max(q[j].x, q[j].z));
    #pragma unroll
    for (int off = 32; off > 0; off >>= 1)
        mx = max(mx, __shfl_down(mx, off, 64));
    if (lane == 0) smax[wv] = mx;
    __syncthreads();
    const int mxq = (max(max(smax[0], smax[1]), max(smax[2], smax[3])) + 1) / KK;

    // ---- phase 2: flat ids + match mask + compaction
    unsigned m16 = 0;
    #pragma unroll
    for (int j = 0; j < 8; ++j) {
        int x0 = q[j].x, y0 = q[j].y, x1 = q[j].z, y1 = q[j].w;
        unsigned f0 = (unsigned)((max(x0, 0) >> 2) + mxq * (max(y0, 0) >> 2));
        unsigned f1 = (unsigned)((max(x1, 0) >> 2) + mxq * (max(y1, 0) >> 2));
        bool p0 = (x0 == -1) && (y0 == -1);
        bool p1 = (x1 == -1) && (y1 == -1);
        if (!p0 && f0 == l) m16 |= 1u << (2 * j);
        if (!p1 && f1 == l) m16 |= 1u << (2 * j + 1);
    }
    int cnt = __popc(m16);

    int pre = cnt;                      // inclusive wave prefix
    #pragma unroll
    for (int off = 1; off < 64; off <<= 1) {
        int n = __shfl_up(pre, off, 64);
        if (lane >= off) pre += n;
    }
    if (lane == 63) wcnt[wv] = pre;
    int excl = pre - cnt;
    __syncthreads();

    int woff = 0;
    #pragma unroll
    for (int v = 0; v < 4; ++v) if (v < wv) woff += wcnt[v];
    int total = wcnt[0] + wcnt[1] + wcnt[2] + wcnt[3];

    int r = woff + excl;
    unsigned m = m16;
    while (m) {
        int j = __ffs(m) - 1;
        m &= m - 1;
        list[r++] = (unsigned short)(tokbase + j);
    }
    __syncthreads();

    // ---- phase 3: gather-sum (288 float4/row; thread t owns col4 t, +t+256 if t<32)
    float4 a0 = make_float4(0.f, 0.f, 0.f, 0.f);
    float4 a1 = make_float4(0.f, 0.f, 0.f, 0.f);
    const float* hb = hs + (size_t)b * SQ * HD;
    int i = 0;
    for (; i + 3 < total; i += 4) {
        const float4* r0 = (const float4*)(hb + (size_t)list[i]     * HD);
        const float4* r1 = (const float4*)(hb + (size_t)list[i + 1] * HD);
        const float4* r2 = (const float4*)(hb + (size_t)list[i + 2] * HD);
        const float4* r3 = (const float4*)(hb + (size_t)list[i + 3] * HD);
        float4 v0 = r0[tid], v1 = r1[tid], v2 = r2[tid], v3 = r3[tid];
        a0.x += v0.x + v1.x + v2.x + v3.x;
        a0.y += v0.y + v1.y + v2.y + v3.y;
        a0.z += v0.z + v1.z + v2.z + v3.z;
        a0.w += v0.w + v1.w + v2.w + v3.w;
        if (tid < HD / 4 - 256) {
            float4 u0 = r0[256 + tid], u1 = r1[256 + tid];
            float4 u2 = r2[256 + tid], u3 = r3[256 + tid];
            a1.x += u0.x + u1.x + u2.x + u3.x;
            a1.y += u0.y + u1.y + u2.y + u3.y;
            a1.z += u0.z + u1.z + u2.z + u3.z;
            a1.w += u0.w + u1.w + u2.w + u3.w;
        }
    }
    for (; i < total; ++i) {
        const float4* r0 = (const float4*)(hb + (size_t)list[i] * HD);
        float4 v0 = r0[tid];
        a0.x += v0.x; a0.y += v0.y; a0.z += v0.z; a0.w += v0.w;
        if (tid < HD / 4 - 256) {
            float4 u0 = r0[256 + tid];
            a1.x += u0.x; a1.y += u0.y; a1.z += u0.z; a1.w += u0.w;
        }
    }

    const float scale = 2.1213203435596424f;   // sqrt(1152) / 16
    float4* o = (float4*)(out + (size_t)bl * HD);
    a0.x *= scale; a0.y *= scale; a0.z *= scale; a0.w *= scale;
    o[tid] = a0;
    if (tid < HD / 4 - 256) {
        a1.x *= scale; a1.y *= scale; a1.z *= scale; a1.w *= scale;
        o[256 + tid] = a1;
    }
    if (tid == 0) mask[bl] = (total > 0) ? 1.0f : 0.0f;
}

extern "C" void kernel_launch(void* const* d_in, const int* in_sizes, int n_in,
                              void* d_out, int out_size, void* d_ws, size_t ws_size,
                              hipStream_t stream) {
    const float* hs = (const float*)d_in[0];
    const int* pos = (const int*)d_in[1];
    float* out = (float*)d_out;                        // pooled [8,256,1152]
    float* mask = out + (size_t)BT * NB * HD;          // mask   [8,256]

    k_pool<<<BT * NB, 256, 0, stream>>>(pos, hs, out, mask);
}